// Round 1
// baseline (232.752 us; speedup 1.0000x reference)
//
#include <hip/hip_runtime.h>
#include <math.h>

// Problem geometry (fixed by the reference)
#define B_ 16
#define C_ 16
#define T_ 32
#define H_ 64
#define W_ 64
#define HW_ (H_ * W_)            // 4096
#define BC_ (B_ * C_)            // 256
#define PER_BC_ ((size_t)T_ * HW_) // 131072 floats per (b,c)

__device__ __forceinline__ double dsigmoid(double v) { return 1.0 / (1.0 + exp(-v)); }

// ---------------------------------------------------------------------------
// Kernel 0: fold the entire linear pipeline into 32 per-t weights + 1 constant.
//   pooled[b,c] = sum_t u[t] * sum_{h,w} x[b,c,t,h,w]  + c0
// where u[t] = v[t]/4096 and v is the adjoint of
//   (multi-scale avgpool -> conv3(wbar,bbar) -> lerp-to-32 -> *scale_w) applied
// to w[t] = ad[t] * attn[t] * twn[t].
// Computed in f64; all interp positions are exact binary fractions so the
// floor/clip decisions match the f32 reference bit-for-bit.
// One block of 64 threads; lanes 32..63 duplicate lanes 0..31 (keeps the
// butterfly shuffles simple and all loads in-bounds).
// ---------------------------------------------------------------------------
__global__ void etad_precompute(
    const float* __restrict__ conv_w,  // [32,1,3]
    const float* __restrict__ conv_b,  // [32]
    const float* __restrict__ scale_w, // [4]
    const float* __restrict__ alpha_p, // [1]
    const float* __restrict__ beta_p,  // [1]
    const float* __restrict__ ti,      // [32]
    const float* __restrict__ av,      // [4,8] flat
    const float* __restrict__ proj_w,  // [32,32]
    const float* __restrict__ proj_b,  // [32]
    const float* __restrict__ td,      // [32]
    const float* __restrict__ ln_g,    // [32]
    const float* __restrict__ ln_b,    // [32]
    float* __restrict__ u_out)         // [33]: u[0..31], c0
{
    const int lane = threadIdx.x;  // 0..63
    const int t = lane & 31;

    // Channel-averaged conv kernel + bias
    double w0 = 0, w1 = 0, w2 = 0, bb = 0;
    for (int ch = 0; ch < T_; ++ch) {
        w0 += (double)conv_w[ch * 3 + 0];
        w1 += (double)conv_w[ch * 3 + 1];
        w2 += (double)conv_w[ch * 3 + 2];
        bb += (double)conv_b[ch];
    }
    w0 /= T_; w1 /= T_; w2 /= T_; bb /= T_;

    // twn[t] = LayerNorm(sigmoid(temporal_dynamics))[t]
    double tw = dsigmoid((double)td[t]);
    double s1 = tw;
    for (int m = 1; m < 32; m <<= 1) s1 += __shfl_xor(s1, m, 64);
    double mean = s1 / 32.0;
    double dv = tw - mean;
    double s2 = dv * dv;
    for (int m = 1; m < 32; m <<= 1) s2 += __shfl_xor(s2, m, 64);
    double var = s2 / 32.0;
    double twn = (tw - mean) / sqrt(var + 1e-5) * (double)ln_g[t] + (double)ln_b[t];

    // attn[t]: softmax over length-1 axis == 1, so the attention output row is
    // exactly attn_value (input-independent). attn_key/pos_encoding are dead.
    double attn = (double)proj_b[t];
    for (int k = 0; k < 32; ++k) attn += (double)av[k] * (double)proj_w[t * 32 + k];

    // Adaptive decay
    double a = (double)alpha_p[0], be = (double)beta_p[0];
    double ad = exp(-a * (double)t) * dsigmoid(be * (double)t) * dsigmoid((double)ti[t]);

    double wt = ad * attn * twn;

    __shared__ double wsh[32];
    if (lane < 32) wsh[t] = wt;
    __syncthreads();

    // Constant term: each scale adds scale_w[i]*bbar uniformly over t
    double sumw = 0;
    for (int k = 0; k < 32; ++k) sumw += wsh[k];
    double sws = (double)scale_w[0] + (double)scale_w[1] + (double)scale_w[2] + (double)scale_w[3];
    double c0 = sumw * bb * sws;

    // v[t] by pushing the basis vector e_t forward through each scale path and
    // dotting with w (gather form of the adjoint; no atomics needed).
    double v = 0;
    for (int i = 0; i < 4; ++i) {
        const int s = 1 << i;
        const int Ts = 32 >> i;
        const int jc = t / s;                 // e_t lands in xs[jc] with value 1/s
        const double swi = (double)scale_w[i];
        const double inv_s = 1.0 / (double)s;
        for (int t2 = 0; t2 < 32; ++t2) {
            double pos = ((double)t2 + 0.5) * ((double)Ts / 32.0) - 0.5;
            if (pos < 0.0) pos = 0.0;
            const double mx = (double)(Ts - 1);
            if (pos > mx) pos = mx;
            int i0 = (int)floor(pos);
            int i1 = i0 + 1; if (i1 > Ts - 1) i1 = Ts - 1;
            double f = pos - (double)i0;
            // y[j] from basis: nonzero only for j-jc in {-1,0,1}
            int d0 = i0 - jc, d1 = i1 - jc;
            double y0 = (d0 == 1) ? w0 : ((d0 == 0) ? w1 : ((d0 == -1) ? w2 : 0.0));
            double y1 = (d1 == 1) ? w0 : ((d1 == 0) ? w1 : ((d1 == -1) ? w2 : 0.0));
            double coef = ((1.0 - f) * y0 + f * y1) * inv_s;
            v += swi * wsh[t2] * coef;
        }
    }

    if (lane < 32) u_out[t] = (float)(v / (double)HW_);
    if (lane == 0) u_out[32] = (float)c0;
}

// ---------------------------------------------------------------------------
// Kernel 1: one block per (b,c). 1024 threads x 32 iterations of float4 loads
// cover the 131072 elements (each iteration = exactly one t-slab of 4096).
// Weighted block reduction, then broadcast-store the 4096 outputs.
// ---------------------------------------------------------------------------
__global__ __launch_bounds__(1024) void etad_main(
    const float* __restrict__ x, const float* __restrict__ u, float* __restrict__ out)
{
    const int bc = blockIdx.x;
    const int tid = threadIdx.x;

    __shared__ float su[33];
    if (tid < 33) su[tid] = u[tid];
    __syncthreads();

    const float4* xb = (const float4*)(x + (size_t)bc * PER_BC_);
    float acc = 0.f;
#pragma unroll
    for (int t = 0; t < T_; ++t) {
        float4 v = xb[t * (HW_ / 4) + tid];
        acc = fmaf(su[t], (v.x + v.y) + (v.z + v.w), acc);
    }

    // wave reduce (64 lanes)
    for (int off = 32; off; off >>= 1) acc += __shfl_down(acc, off, 64);

    __shared__ float wsum[16];
    __shared__ float pooled_s;
    const int wid = tid >> 6;
    if ((tid & 63) == 0) wsum[wid] = acc;
    __syncthreads();
    if (tid == 0) {
        float s = 0.f;
#pragma unroll
        for (int i = 0; i < 16; ++i) s += wsum[i];
        pooled_s = s + su[32];
    }
    __syncthreads();

    const float p = pooled_s;
    float4 o = make_float4(p, p, p, p);
    ((float4*)(out + (size_t)bc * HW_))[tid] = o;
}

extern "C" void kernel_launch(void* const* d_in, const int* in_sizes, int n_in,
                              void* d_out, int out_size, void* d_ws, size_t ws_size,
                              hipStream_t stream) {
    const float* x      = (const float*)d_in[0];
    const float* conv_w = (const float*)d_in[1];
    const float* conv_b = (const float*)d_in[2];
    const float* sw     = (const float*)d_in[3];
    const float* alpha  = (const float*)d_in[4];
    const float* beta   = (const float*)d_in[5];
    const float* ti     = (const float*)d_in[6];
    // d_in[7] attn_key: dead (softmax over a length-1 axis == 1)
    const float* av     = (const float*)d_in[8];
    // d_in[9] pos_encoding: dead (only feeds the softmaxed-away scores)
    const float* pw     = (const float*)d_in[10];
    const float* pb     = (const float*)d_in[11];
    const float* td     = (const float*)d_in[12];
    const float* lg     = (const float*)d_in[13];
    const float* lb     = (const float*)d_in[14];

    float* out = (float*)d_out;
    float* u   = (float*)d_ws;  // 33 floats of scratch

    etad_precompute<<<1, 64, 0, stream>>>(conv_w, conv_b, sw, alpha, beta, ti,
                                          av, pw, pb, td, lg, lb, u);
    etad_main<<<BC_, 1024, 0, stream>>>(x, u, out);
}

// Round 3
// 213.746 us; speedup vs baseline: 1.0889x; 1.0889x over previous
//
#include <hip/hip_runtime.h>
#include <math.h>

// Problem geometry (fixed by the reference)
#define B_ 16
#define C_ 16
#define T_ 32
#define H_ 64
#define W_ 64
#define HW_ (H_ * W_)              // 4096
#define BC_ (B_ * C_)              // 256
#define PER_BC_ ((size_t)T_ * HW_) // 131072 floats per (b,c)

__device__ __forceinline__ double dsigmoid(double v) { return 1.0 / (1.0 + exp(-v)); }

// ---------------------------------------------------------------------------
// Single fused kernel. One block per (b,c), 1024 threads = 16 waves.
//
// Math (verified exact in Round 1, absmax 0.0):
//   pooled[b,c] = c0 + sum_t u[t] * S[t],  S[t] = sum_{h,w} x[b,c,t,h,w]
// where u/c0 fold the whole linear pipeline (multi-scale avgpool -> conv3
// channel-mean -> trilinear lerp -> scale_w, times ad[t]*attn[t]*twn[t],
// divided by 4096 for the spatial mean). softmax over a length-1 axis == 1,
// so attn_key/pos_encoding are dead and attn[t] = proj_w[t,:]@attn_value+proj_b.
//
// Raw slab sums S[t] don't need the coefficients, so waves 1..15 stream
// immediately; wave 0 computes the 33 f64 coefficients (shuffle-only, no LDS
// deps) and then streams its own two slabs. Coefficient VALU time hides under
// the block's 512 KB of HBM traffic.
// ---------------------------------------------------------------------------
__global__ __launch_bounds__(1024) void etad_fused(
    const float* __restrict__ x,
    const float* __restrict__ conv_w,  // [32,1,3]
    const float* __restrict__ conv_b,  // [32]
    const float* __restrict__ scale_w, // [4]
    const float* __restrict__ alpha_p, // [1]
    const float* __restrict__ beta_p,  // [1]
    const float* __restrict__ ti,      // [32]
    const float* __restrict__ av,      // [4,8] flat
    const float* __restrict__ proj_w,  // [32,32]
    const float* __restrict__ proj_b,  // [32]
    const float* __restrict__ td,      // [32]
    const float* __restrict__ ln_g,    // [32]
    const float* __restrict__ ln_b,    // [32]
    float* __restrict__ out)
{
    const int tid  = threadIdx.x;
    const int lane = tid & 63;
    const int wid  = tid >> 6;   // 0..15
    const int bc   = blockIdx.x;

    __shared__ float su[33];     // u[0..31], c0
    __shared__ float S[32];      // raw slab sums
    __shared__ float pooled_s;

    // ---- wave 0: fold the linear pipeline into u[33] (f64, shuffle-only) ----
    if (wid == 0) {
        const int t = lane & 31;

        // channel-averaged conv kernel + bias
        double w0 = 0, w1 = 0, w2 = 0, bb = 0;
        for (int ch = 0; ch < T_; ++ch) {
            w0 += (double)conv_w[ch * 3 + 0];
            w1 += (double)conv_w[ch * 3 + 1];
            w2 += (double)conv_w[ch * 3 + 2];
            bb += (double)conv_b[ch];
        }
        w0 /= T_; w1 /= T_; w2 /= T_; bb /= T_;

        // twn = LayerNorm(sigmoid(temporal_dynamics))
        double tw = dsigmoid((double)td[t]);
        double s1 = tw;
        for (int m = 1; m < 32; m <<= 1) s1 += __shfl_xor(s1, m, 64);
        double mean = s1 / 32.0;
        double dv = tw - mean;
        double s2 = dv * dv;
        for (int m = 1; m < 32; m <<= 1) s2 += __shfl_xor(s2, m, 64);
        double var = s2 / 32.0;
        double twn = (tw - mean) / sqrt(var + 1e-5) * (double)ln_g[t] + (double)ln_b[t];

        // attn[t] = proj_w[t,:] @ attn_value + proj_b[t]  (softmax(len-1)==1)
        double attn = (double)proj_b[t];
        for (int k = 0; k < 32; ++k) attn += (double)av[k] * (double)proj_w[t * 32 + k];

        // adaptive decay
        double a = (double)alpha_p[0], be = (double)beta_p[0];
        double ad = exp(-a * (double)t) * dsigmoid(be * (double)t) * dsigmoid((double)ti[t]);

        double wt = ad * attn * twn;

        // constant term: each scale adds scale_w[i]*bbar uniformly over t
        double sumw = wt;
        for (int m = 1; m < 32; m <<= 1) sumw += __shfl_xor(sumw, m, 64);
        double sws = (double)scale_w[0] + (double)scale_w[1] + (double)scale_w[2] + (double)scale_w[3];
        double c0 = sumw * bb * sws;

        // v[t]: push basis e_t through each scale path, dot with wt (gathered
        // via width-32 broadcast shuffles; both wave halves hold the full t set)
        double v = 0;
        for (int i = 0; i < 4; ++i) {
            const int s = 1 << i;
            const int Ts = 32 >> i;
            const int jc = t >> i;
            const double swi = (double)scale_w[i];
            const double inv_s = 1.0 / (double)s;
            for (int t2 = 0; t2 < 32; ++t2) {
                double pos = ((double)t2 + 0.5) * ((double)Ts / 32.0) - 0.5;
                if (pos < 0.0) pos = 0.0;
                const double mx = (double)(Ts - 1);
                if (pos > mx) pos = mx;
                int i0 = (int)floor(pos);
                int i1 = i0 + 1; if (i1 > Ts - 1) i1 = Ts - 1;
                double f = pos - (double)i0;
                int d0 = i0 - jc, d1 = i1 - jc;
                double y0 = (d0 == 1) ? w0 : ((d0 == 0) ? w1 : ((d0 == -1) ? w2 : 0.0));
                double y1 = (d1 == 1) ? w0 : ((d1 == 0) ? w1 : ((d1 == -1) ? w2 : 0.0));
                double coef = ((1.0 - f) * y0 + f * y1) * inv_s;
                double wt2 = __shfl(wt, t2, 32);
                v += swi * wt2 * coef;
            }
        }

        if (lane < 32) su[t] = (float)(v / (double)HW_);
        if (lane == 0) su[32] = (float)c0;
    }

    // ---- all waves: stream slabs 2*wid and 2*wid+1 (512 KB per block) ----
    const float4* xb = (const float4*)(x + (size_t)bc * PER_BC_);
    const float4* p0 = xb + (size_t)(2 * wid) * (HW_ / 4) + lane;
    const float4* p1 = p0 + (HW_ / 4);
    float acc0 = 0.f, acc1 = 0.f;
#pragma unroll
    for (int i = 0; i < 16; ++i) {
        float4 a4 = p0[i * 64];
        float4 b4 = p1[i * 64];
        acc0 += (a4.x + a4.y) + (a4.z + a4.w);
        acc1 += (b4.x + b4.y) + (b4.z + b4.w);
    }
    for (int off = 32; off; off >>= 1) {
        acc0 += __shfl_down(acc0, off, 64);
        acc1 += __shfl_down(acc1, off, 64);
    }
    if (lane == 0) { S[2 * wid] = acc0; S[2 * wid + 1] = acc1; }
    __syncthreads();

    if (tid == 0) {
        float pooled = su[32];
#pragma unroll
        for (int t = 0; t < T_; ++t) pooled = fmaf(su[t], S[t], pooled);
        pooled_s = pooled;
    }
    __syncthreads();

    const float p = pooled_s;
    ((float4*)(out + (size_t)bc * HW_))[tid] = make_float4(p, p, p, p);
}

extern "C" void kernel_launch(void* const* d_in, const int* in_sizes, int n_in,
                              void* d_out, int out_size, void* d_ws, size_t ws_size,
                              hipStream_t stream) {
    const float* x      = (const float*)d_in[0];
    const float* conv_w = (const float*)d_in[1];
    const float* conv_b = (const float*)d_in[2];
    const float* sw     = (const float*)d_in[3];
    const float* alpha  = (const float*)d_in[4];
    const float* beta   = (const float*)d_in[5];
    const float* ti     = (const float*)d_in[6];
    // d_in[7] attn_key: dead (softmax over a length-1 axis == 1)
    const float* av     = (const float*)d_in[8];
    // d_in[9] pos_encoding: dead (only feeds the softmaxed-away scores)
    const float* pw     = (const float*)d_in[10];
    const float* pb     = (const float*)d_in[11];
    const float* td     = (const float*)d_in[12];
    const float* lg     = (const float*)d_in[13];
    const float* lb     = (const float*)d_in[14];

    float* out = (float*)d_out;

    etad_fused<<<BC_, 1024, 0, stream>>>(x, conv_w, conv_b, sw, alpha, beta, ti,
                                         av, pw, pb, td, lg, lb, out);
}